// Round 6
// baseline (261.247 us; speedup 1.0000x reference)
//
#include <hip/hip_runtime.h>

#define N_NODES 50000
#define N_EDGES 800000
#define N_GRAPHS 128
#define IN_DIM 256
#define OUT_DIM 128
#define NEG_SLOPE 0.01f

#define BM 64
#define BK 32
#define RCHUNK 64
#define NB_SCAN ((N_NODES + 255) / 256)   // 196 blocks for the scan

#define NSLICE 4
#define SLICE 12544                        // 4*12544 = 50176 >= N_NODES
#define NTOT (NSLICE * SLICE)              // 50176
#define NCHUNK 64
#define NE4 (N_EDGES / 4)                  // 200000 int4 quads
#define QPC (NE4 / NCHUNK)                 // 3125 quads per chunk

// ---------------- degree histograms: LDS slices, zero global atomics ----------------
// grid = 2 hists x 4 slices x 64 chunks = 512 blocks.
__global__ __launch_bounds__(256) void deg_kernel(const int4* __restrict__ src4,
                                                  const int4* __restrict__ dst4,
                                                  int* __restrict__ rep) {
    __shared__ int bins[SLICE];
    int b     = blockIdx.x;
    int hist  = b >> 8;                  // 0: src (out-deg), 1: dst (in-deg)
    int rem   = b & 255;
    int slice = rem >> 6;
    int chunk = rem & 63;
    const int4* ea = hist ? dst4 : src4;
    int lo = slice * SLICE;

    for (int i = threadIdx.x; i < SLICE; i += 256) bins[i] = 0;
    __syncthreads();

    int q0 = chunk * QPC;
    int q1 = q0 + QPC;
    for (int q = q0 + threadIdx.x; q < q1; q += 256) {
        int4 e = ea[q];
        unsigned a0 = (unsigned)(e.x - lo); if (a0 < SLICE) atomicAdd(&bins[a0], 1);
        unsigned a1 = (unsigned)(e.y - lo); if (a1 < SLICE) atomicAdd(&bins[a1], 1);
        unsigned a2 = (unsigned)(e.z - lo); if (a2 < SLICE) atomicAdd(&bins[a2], 1);
        unsigned a3 = (unsigned)(e.w - lo); if (a3 < SLICE) atomicAdd(&bins[a3], 1);
    }
    __syncthreads();

    int* rp = rep + (size_t)(hist * NCHUNK + chunk) * NTOT + lo;
    for (int i = threadIdx.x; i < SLICE / 4; i += 256)
        *(int4*)&rp[i * 4] = *(const int4*)&bins[i * 4];
}

// ---------------- reduce replicas -> norms + deg_in; in-place chunk-prefix scan ----------------
__global__ __launch_bounds__(256) void norm_kernel(int* __restrict__ rep,
                                                   float* __restrict__ out_norm,
                                                   float* __restrict__ in_norm,
                                                   int* __restrict__ deg_in_tot) {
    int i = blockIdx.x * 256 + threadIdx.x;
    if (i < N_NODES) {
        int so = 0;
#pragma unroll
        for (int c = 0; c < NCHUNK; ++c) so += rep[(size_t)c * NTOT + i];
        int si = 0;
#pragma unroll
        for (int c = 0; c < NCHUNK; ++c) {       // exclusive scan, in place
            size_t off = (size_t)(NCHUNK + c) * NTOT + i;
            int v = rep[off];
            rep[off] = si;
            si += v;
        }
        deg_in_tot[i] = si;
        int dq = so > 1 ? so : 1;
        int di = si > 1 ? si : 1;
        out_norm[i] = rsqrtf((float)dq);
        in_norm[i]  = rsqrtf((float)di);
    }
}

// ---------------- multi-block scan phase 1: per-block sums ----------------
__global__ __launch_bounds__(256) void partial_kernel(const int* __restrict__ deg_in,
                                                      int* __restrict__ bsum) {
    __shared__ int red[256];
    int t   = threadIdx.x;
    int idx = blockIdx.x * 256 + t;
    red[t] = (idx < N_NODES) ? deg_in[idx] : 0;
    __syncthreads();
    for (int off = 128; off > 0; off >>= 1) {
        if (t < off) red[t] += red[t + off];
        __syncthreads();
    }
    if (t == 0) bsum[blockIdx.x] = red[0];
}

// ---------------- phase 2: scan the 196 block sums (one block) ----------------
__global__ __launch_bounds__(256) void scan_bsums(const int* __restrict__ bsum,
                                                  int* __restrict__ bofs,
                                                  int* __restrict__ row_ofs) {
    __shared__ int sh[256];
    int t = threadIdx.x;
    int v = (t < NB_SCAN) ? bsum[t] : 0;
    sh[t] = v;
    __syncthreads();
    for (int off = 1; off < 256; off <<= 1) {
        int a = sh[t];
        int b = (t >= off) ? sh[t - off] : 0;
        __syncthreads();
        sh[t] = a + b;
        __syncthreads();
    }
    if (t < NB_SCAN) bofs[t] = sh[t] - v;                    // exclusive
    if (t == 255)    row_ofs[N_NODES] = sh[NB_SCAN - 1];     // total (= N_EDGES)
}

// ---------------- phase 3: block-local scan + offset -> row_ofs ----------------
__global__ __launch_bounds__(256) void fill_kernel(const int* __restrict__ deg_in,
                                                   const int* __restrict__ bofs,
                                                   int* __restrict__ row_ofs) {
    __shared__ int sh[256];
    int t   = threadIdx.x;
    int idx = blockIdx.x * 256 + t;
    int v   = (idx < N_NODES) ? deg_in[idx] : 0;
    sh[t] = v;
    __syncthreads();
    for (int off = 1; off < 256; off <<= 1) {
        int a = sh[t];
        int b = (t >= off) ? sh[t - off] : 0;
        __syncthreads();
        sh[t] = a + b;
        __syncthreads();
    }
    if (idx < N_NODES) row_ofs[idx] = bofs[blockIdx.x] + sh[t] - v;
}

// ---------------- chunked bucket fill: LDS cursors, zero global atomics ----------------
// grid = 4 slices x 64 chunks = 256 blocks. Cursor = row_ofs + per-chunk prefix.
__global__ __launch_bounds__(256) void build_kernel(const int4* __restrict__ src4,
                                                    const int4* __restrict__ dst4,
                                                    const int* __restrict__ row_ofs,
                                                    const int* __restrict__ rep,
                                                    int* __restrict__ esrc) {
    __shared__ int cur[SLICE];
    int b     = blockIdx.x;
    int slice = b >> 6;
    int chunk = b & 63;
    int lo    = slice * SLICE;
    const int* rel = rep + (size_t)(NCHUNK + chunk) * NTOT + lo;

    for (int i = threadIdx.x; i < SLICE; i += 256) {
        int n = lo + i;
        int r = (n < N_NODES) ? row_ofs[n] : 0;
        cur[i] = r + rel[i];
    }
    __syncthreads();

    int q0 = chunk * QPC;
    int q1 = q0 + QPC;
    for (int q = q0 + threadIdx.x; q < q1; q += 256) {
        int4 s = src4[q];
        int4 d = dst4[q];
        unsigned a0 = (unsigned)(d.x - lo); if (a0 < SLICE) esrc[atomicAdd(&cur[a0], 1)] = s.x;
        unsigned a1 = (unsigned)(d.y - lo); if (a1 < SLICE) esrc[atomicAdd(&cur[a1], 1)] = s.y;
        unsigned a2 = (unsigned)(d.z - lo); if (a2 < SLICE) esrc[atomicAdd(&cur[a2], 1)] = s.z;
        unsigned a3 = (unsigned)(d.w - lo); if (a3 < SLICE) esrc[atomicAdd(&cur[a3], 1)] = s.w;
    }
}

// ---------------- fold Wc = w_red @ w2, bc = b_red @ w2 ----------------
__global__ __launch_bounds__(128) void wc_kernel(const float* __restrict__ w_red,
                                                 const float* __restrict__ b_red,
                                                 const float* __restrict__ w2,
                                                 float* __restrict__ Wc,
                                                 float* __restrict__ bc) {
    int j = threadIdx.x;   // 0..127
    int i = blockIdx.x;    // 0..256 (block 256 computes bc)
    const float* vin = (i < IN_DIM) ? (w_red + (size_t)i * OUT_DIM) : b_red;
    float s = 0.f;
    for (int k = 0; k < OUT_DIM; ++k) s = fmaf(vin[k], w2[k * OUT_DIM + j], s);
    if (i < IN_DIM) Wc[i * OUT_DIM + j] = s;
    else            bc[j] = s;
}

// ---------------- z = out_norm * (feat @ Wc + bc) ----------------
// Register-staged double-buffered tiles: global loads for tile t+1 issue before
// computing tile t; one barrier per iteration. Ast stride 69 -> uniform 2-way
// (free) staging writes; B-cols split {cg*4, 64+cg*4} -> 2-way read conflicts.
__global__ __launch_bounds__(256) void gemm_z(const float* __restrict__ feat,
                                              const float* __restrict__ Wc,
                                              const float* __restrict__ bc,
                                              const float* __restrict__ out_norm,
                                              float* __restrict__ z) {
    __shared__ float Ast[2][BK][BM + 5];     // [buf][k][row], stride 69
    __shared__ float Bs[2][BK][OUT_DIM];

    int t   = threadIdx.x;
    int bm  = blockIdx.x * BM;
    int cg  = t & 15;      // cols cg*4..+3 and 64+cg*4..+3
    int rg  = t >> 4;      // rows rg*4..+3
    int ar  = t >> 3;      // staging: rows ar, ar+32
    int ak  = (t & 7) * 4; // staging: k-offsets ak..ak+3
    int bn  = (t & 31) * 4;
    int bk0 = t >> 5;      // staging: B rows bk0 + 8i

    int gm0 = bm + ar;
    int gm1 = bm + ar + 32;
    const float* fp0 = feat + (size_t)gm0 * IN_DIM + ak;
    const float* fp1 = feat + (size_t)gm1 * IN_DIM + ak;

    float acc[4][8];
#pragma unroll
    for (int i = 0; i < 4; ++i)
#pragma unroll
        for (int j = 0; j < 8; ++j) acc[i][j] = 0.f;

    float4 av0, av1, bv0, bv1, bv2, bv3;
    const float4 zf4 = make_float4(0.f, 0.f, 0.f, 0.f);

#define LOADT(k0)                                                              \
    av0 = (gm0 < N_NODES) ? *(const float4*)(fp0 + (k0)) : zf4;                \
    av1 = (gm1 < N_NODES) ? *(const float4*)(fp1 + (k0)) : zf4;                \
    bv0 = *(const float4*)&Wc[(size_t)((k0) + bk0     ) * OUT_DIM + bn];       \
    bv1 = *(const float4*)&Wc[(size_t)((k0) + bk0 +  8) * OUT_DIM + bn];       \
    bv2 = *(const float4*)&Wc[(size_t)((k0) + bk0 + 16) * OUT_DIM + bn];       \
    bv3 = *(const float4*)&Wc[(size_t)((k0) + bk0 + 24) * OUT_DIM + bn];

#define STORET(buf)                                                            \
    Ast[buf][ak + 0][ar]      = av0.x; Ast[buf][ak + 1][ar]      = av0.y;      \
    Ast[buf][ak + 2][ar]      = av0.z; Ast[buf][ak + 3][ar]      = av0.w;      \
    Ast[buf][ak + 0][ar + 32] = av1.x; Ast[buf][ak + 1][ar + 32] = av1.y;      \
    Ast[buf][ak + 2][ar + 32] = av1.z; Ast[buf][ak + 3][ar + 32] = av1.w;      \
    *(float4*)&Bs[buf][bk0     ][bn] = bv0;                                    \
    *(float4*)&Bs[buf][bk0 +  8][bn] = bv1;                                    \
    *(float4*)&Bs[buf][bk0 + 16][bn] = bv2;                                    \
    *(float4*)&Bs[buf][bk0 + 24][bn] = bv3;

    LOADT(0);
    STORET(0);
    __syncthreads();

    const int NT = IN_DIM / BK;   // 8 tiles
    for (int tile = 0; tile < NT; ++tile) {
        int buf = tile & 1;
        if (tile < NT - 1) { LOADT((tile + 1) * BK); }   // in flight during compute
#pragma unroll
        for (int k = 0; k < BK; ++k) {
            float4 a4 = *(const float4*)&Ast[buf][k][rg * 4];
            float a[4] = {a4.x, a4.y, a4.z, a4.w};
            float4 b0 = *(const float4*)&Bs[buf][k][cg * 4];
            float4 b1 = *(const float4*)&Bs[buf][k][64 + cg * 4];
            float bb[8] = {b0.x, b0.y, b0.z, b0.w, b1.x, b1.y, b1.z, b1.w};
#pragma unroll
            for (int i = 0; i < 4; ++i)
#pragma unroll
                for (int j = 0; j < 8; ++j)
                    acc[i][j] = fmaf(a[i], bb[j], acc[i][j]);
        }
        if (tile < NT - 1) {
            STORET(buf ^ 1);       // waits on the global loads (auto s_waitcnt)
            __syncthreads();       // publish for next iteration
        }
    }
#undef LOADT
#undef STORET

#pragma unroll
    for (int i = 0; i < 4; ++i) {
        int gm = bm + rg * 4 + i;
        if (gm < N_NODES) {
            float on = out_norm[gm];
            float4 o0, o1;
            o0.x = on * (acc[i][0] + bc[cg * 4 + 0]);
            o0.y = on * (acc[i][1] + bc[cg * 4 + 1]);
            o0.z = on * (acc[i][2] + bc[cg * 4 + 2]);
            o0.w = on * (acc[i][3] + bc[cg * 4 + 3]);
            o1.x = on * (acc[i][4] + bc[64 + cg * 4 + 0]);
            o1.y = on * (acc[i][5] + bc[64 + cg * 4 + 1]);
            o1.z = on * (acc[i][6] + bc[64 + cg * 4 + 2]);
            o1.w = on * (acc[i][7] + bc[64 + cg * 4 + 3]);
            *(float4*)&z[(size_t)gm * OUT_DIM + cg * 4]      = o0;
            *(float4*)&z[(size_t)gm * OUT_DIM + 64 + cg * 4] = o1;
        }
    }
}

// ---------------- pull-model aggregate + fused in_norm/bias/leaky_relu ----------------
__global__ __launch_bounds__(128) void gather_kernel(const float* __restrict__ z,
                                                     const int* __restrict__ esrc,
                                                     const int* __restrict__ row_ofs,
                                                     const float* __restrict__ in_norm,
                                                     const float* __restrict__ b2,
                                                     float* __restrict__ h) {
    int n = blockIdx.x;
    int j = threadIdx.x;
    int e0 = row_ofs[n];
    int e1 = row_ofs[n + 1];
    float acc = 0.f;
    int e = e0;
    for (; e + 4 <= e1; e += 4) {
        int sa = esrc[e + 0];
        int sb = esrc[e + 1];
        int sc = esrc[e + 2];
        int sd = esrc[e + 3];
        float va = z[(size_t)sa * OUT_DIM + j];
        float vb = z[(size_t)sb * OUT_DIM + j];
        float vc = z[(size_t)sc * OUT_DIM + j];
        float vd = z[(size_t)sd * OUT_DIM + j];
        acc += (va + vb) + (vc + vd);
    }
    for (; e < e1; ++e) acc += z[(size_t)esrc[e] * OUT_DIM + j];
    float hv = in_norm[n] * acc + b2[j];
    h[(size_t)n * OUT_DIM + j] = (hv > 0.f) ? hv : NEG_SLOPE * hv;
}

// ---------------- per-graph readout (graph_ids sorted) ----------------
__global__ __launch_bounds__(128) void readout_kernel(const float* __restrict__ h,
                                                      const int* __restrict__ gids,
                                                      float* __restrict__ g) {
    int j    = threadIdx.x;
    int n0   = blockIdx.x * RCHUNK;
    int nend = n0 + RCHUNK;
    if (nend > N_NODES) nend = N_NODES;
    float acc = 0.f;
    int   cur = gids[n0];
    for (int n = n0; n < nend; ++n) {
        int gid = gids[n];
        if (gid != cur) {
            atomicAdd(&g[cur * OUT_DIM + j], acc);
            acc = 0.f;
            cur = gid;
        }
        acc += h[(size_t)n * OUT_DIM + j];
    }
    atomicAdd(&g[cur * OUT_DIM + j], acc);
}

// ---------------- classifier: out = g @ w_cls + b_cls ----------------
__global__ __launch_bounds__(256) void cls_kernel(const float* __restrict__ g,
                                                  const float* __restrict__ w_cls,
                                                  const float* __restrict__ b_cls,
                                                  float* __restrict__ out) {
    int t  = threadIdx.x;
    int gr = t >> 1;
    int c  = t & 1;
    float s = b_cls[c];
    for (int k = 0; k < OUT_DIM; ++k) s = fmaf(g[gr * OUT_DIM + k], w_cls[k * 2 + c], s);
    out[t] = s;
}

extern "C" void kernel_launch(void* const* d_in, const int* in_sizes, int n_in,
                              void* d_out, int out_size, void* d_ws, size_t ws_size,
                              hipStream_t stream) {
    const float* feat  = (const float*)d_in[0];
    const int*   src   = (const int*)d_in[1];
    const int*   dst   = (const int*)d_in[2];
    const int*   gids  = (const int*)d_in[3];
    const float* w_red = (const float*)d_in[4];
    const float* b_red = (const float*)d_in[5];
    const float* w_gcn = (const float*)d_in[6];
    const float* b_gcn = (const float*)d_in[7];
    const float* w_cls = (const float*)d_in[8];
    const float* b_cls = (const float*)d_in[9];
    float* out = (float*)d_out;

    // workspace layout
    float* z        = (float*)d_ws;                       // 6.4M floats (25.6MB)
    float* h        = z + (size_t)N_NODES * OUT_DIM;      // 6.4M floats (25.6MB)
    float* out_norm = h + (size_t)N_NODES * OUT_DIM;      // 50000
    float* in_norm  = out_norm + N_NODES;                 // 50000
    int*   deg_in   = (int*)(in_norm + N_NODES);          // 50000 (compact)
    int*   row_ofs  = deg_in + N_NODES;                   // 50001
    int*   esrc     = row_ofs + N_NODES + 1;              // 800000
    int*   bsum     = esrc + N_EDGES;                     // NB_SCAN
    int*   bofs     = bsum + NB_SCAN;                     // NB_SCAN
    float* Wc       = (float*)(bofs + NB_SCAN);           // 32768
    float* bc       = Wc + IN_DIM * OUT_DIM;              // 128
    float* g        = bc + OUT_DIM;                       // 16384

    // per-chunk histogram replicas rep[2][NCHUNK][NTOT] = 25.7MB ALIAS z∪h
    // (deg/norm/build all complete before gemm_z writes z / gather writes h).
    int* rep = (int*)z;

    const float* w2 = w_gcn + 2 * OUT_DIM * OUT_DIM;      // layer 2 weights
    const float* b2 = b_gcn + 2 * OUT_DIM;                // layer 2 bias

    hipMemsetAsync(g, 0, (size_t)N_GRAPHS * OUT_DIM * sizeof(float), stream);

    deg_kernel<<<2 * NSLICE * NCHUNK, 256, 0, stream>>>((const int4*)src, (const int4*)dst, rep);
    norm_kernel<<<(N_NODES + 255) / 256, 256, 0, stream>>>(rep, out_norm, in_norm, deg_in);
    partial_kernel<<<NB_SCAN, 256, 0, stream>>>(deg_in, bsum);
    scan_bsums<<<1, 256, 0, stream>>>(bsum, bofs, row_ofs);
    fill_kernel<<<NB_SCAN, 256, 0, stream>>>(deg_in, bofs, row_ofs);
    build_kernel<<<NSLICE * NCHUNK, 256, 0, stream>>>((const int4*)src, (const int4*)dst,
                                                      row_ofs, rep, esrc);
    wc_kernel<<<IN_DIM + 1, OUT_DIM, 0, stream>>>(w_red, b_red, w2, Wc, bc);
    gemm_z<<<(N_NODES + BM - 1) / BM, 256, 0, stream>>>(feat, Wc, bc, out_norm, z);
    gather_kernel<<<N_NODES, 128, 0, stream>>>(z, esrc, row_ofs, in_norm, b2, h);
    readout_kernel<<<(N_NODES + RCHUNK - 1) / RCHUNK, 128, 0, stream>>>(h, gids, g);
    cls_kernel<<<1, 256, 0, stream>>>(g, w_cls, b_cls, out);
}

// Round 7
// 219.542 us; speedup vs baseline: 1.1900x; 1.1900x over previous
//
#include <hip/hip_runtime.h>

#define N_NODES 50000
#define N_EDGES 800000
#define N_GRAPHS 128
#define IN_DIM 256
#define OUT_DIM 128
#define NEG_SLOPE 0.01f

#define BM 64
#define BN 64
#define BK 32
#define RCHUNK 64
#define NB_SCAN ((N_NODES + 255) / 256)   // 196 blocks for the scan

#define NSLICE 4
#define SLICE 12544                        // 4*12544 = 50176 >= N_NODES
#define NTOT (NSLICE * SLICE)              // 50176
#define NCHUNK 64
#define NE4 (N_EDGES / 4)                  // 200000 int4 quads
#define QPC (NE4 / NCHUNK)                 // 3125 quads per chunk

// ---------------- degree histograms: LDS slices, zero global atomics ----------------
// grid = 2 hists x 4 slices x 64 chunks = 512 blocks.
__global__ __launch_bounds__(256) void deg_kernel(const int4* __restrict__ src4,
                                                  const int4* __restrict__ dst4,
                                                  int* __restrict__ rep) {
    __shared__ int bins[SLICE];
    int b     = blockIdx.x;
    int hist  = b >> 8;                  // 0: src (out-deg), 1: dst (in-deg)
    int rem   = b & 255;
    int slice = rem >> 6;
    int chunk = rem & 63;
    const int4* ea = hist ? dst4 : src4;
    int lo = slice * SLICE;

    for (int i = threadIdx.x; i < SLICE; i += 256) bins[i] = 0;
    __syncthreads();

    int q0 = chunk * QPC;
    int q1 = q0 + QPC;
    for (int q = q0 + threadIdx.x; q < q1; q += 256) {
        int4 e = ea[q];
        unsigned a0 = (unsigned)(e.x - lo); if (a0 < SLICE) atomicAdd(&bins[a0], 1);
        unsigned a1 = (unsigned)(e.y - lo); if (a1 < SLICE) atomicAdd(&bins[a1], 1);
        unsigned a2 = (unsigned)(e.z - lo); if (a2 < SLICE) atomicAdd(&bins[a2], 1);
        unsigned a3 = (unsigned)(e.w - lo); if (a3 < SLICE) atomicAdd(&bins[a3], 1);
    }
    __syncthreads();

    int* rp = rep + (size_t)(hist * NCHUNK + chunk) * NTOT + lo;
    for (int i = threadIdx.x; i < SLICE / 4; i += 256)
        *(int4*)&rp[i * 4] = *(const int4*)&bins[i * 4];
}

// ---------------- reduce replicas -> norms + deg_in; in-place chunk-prefix scan ----------------
__global__ __launch_bounds__(256) void norm_kernel(int* __restrict__ rep,
                                                   float* __restrict__ out_norm,
                                                   float* __restrict__ in_norm,
                                                   int* __restrict__ deg_in_tot) {
    int i = blockIdx.x * 256 + threadIdx.x;
    if (i < N_NODES) {
        int so = 0;
#pragma unroll
        for (int c = 0; c < NCHUNK; ++c) so += rep[(size_t)c * NTOT + i];
        int si = 0;
#pragma unroll
        for (int c = 0; c < NCHUNK; ++c) {       // exclusive scan, in place
            size_t off = (size_t)(NCHUNK + c) * NTOT + i;
            int v = rep[off];
            rep[off] = si;
            si += v;
        }
        deg_in_tot[i] = si;
        int dq = so > 1 ? so : 1;
        int di = si > 1 ? si : 1;
        out_norm[i] = rsqrtf((float)dq);
        in_norm[i]  = rsqrtf((float)di);
    }
}

// ---------------- multi-block scan phase 1: per-block sums ----------------
__global__ __launch_bounds__(256) void partial_kernel(const int* __restrict__ deg_in,
                                                      int* __restrict__ bsum) {
    __shared__ int red[256];
    int t   = threadIdx.x;
    int idx = blockIdx.x * 256 + t;
    red[t] = (idx < N_NODES) ? deg_in[idx] : 0;
    __syncthreads();
    for (int off = 128; off > 0; off >>= 1) {
        if (t < off) red[t] += red[t + off];
        __syncthreads();
    }
    if (t == 0) bsum[blockIdx.x] = red[0];
}

// ---------------- phase 2: scan the 196 block sums (one block) ----------------
__global__ __launch_bounds__(256) void scan_bsums(const int* __restrict__ bsum,
                                                  int* __restrict__ bofs,
                                                  int* __restrict__ row_ofs) {
    __shared__ int sh[256];
    int t = threadIdx.x;
    int v = (t < NB_SCAN) ? bsum[t] : 0;
    sh[t] = v;
    __syncthreads();
    for (int off = 1; off < 256; off <<= 1) {
        int a = sh[t];
        int b = (t >= off) ? sh[t - off] : 0;
        __syncthreads();
        sh[t] = a + b;
        __syncthreads();
    }
    if (t < NB_SCAN) bofs[t] = sh[t] - v;                    // exclusive
    if (t == 255)    row_ofs[N_NODES] = sh[NB_SCAN - 1];     // total (= N_EDGES)
}

// ---------------- phase 3: block-local scan + offset -> row_ofs ----------------
__global__ __launch_bounds__(256) void fill_kernel(const int* __restrict__ deg_in,
                                                   const int* __restrict__ bofs,
                                                   int* __restrict__ row_ofs) {
    __shared__ int sh[256];
    int t   = threadIdx.x;
    int idx = blockIdx.x * 256 + t;
    int v   = (idx < N_NODES) ? deg_in[idx] : 0;
    sh[t] = v;
    __syncthreads();
    for (int off = 1; off < 256; off <<= 1) {
        int a = sh[t];
        int b = (t >= off) ? sh[t - off] : 0;
        __syncthreads();
        sh[t] = a + b;
        __syncthreads();
    }
    if (idx < N_NODES) row_ofs[idx] = bofs[blockIdx.x] + sh[t] - v;
}

// ---------------- chunked bucket fill: LDS cursors, zero global atomics ----------------
// grid = 4 slices x 64 chunks = 256 blocks. Cursor = row_ofs + per-chunk prefix.
__global__ __launch_bounds__(256) void build_kernel(const int4* __restrict__ src4,
                                                    const int4* __restrict__ dst4,
                                                    const int* __restrict__ row_ofs,
                                                    const int* __restrict__ rep,
                                                    int* __restrict__ esrc) {
    __shared__ int cur[SLICE];
    int b     = blockIdx.x;
    int slice = b >> 6;
    int chunk = b & 63;
    int lo    = slice * SLICE;
    const int* rel = rep + (size_t)(NCHUNK + chunk) * NTOT + lo;

    for (int i = threadIdx.x; i < SLICE; i += 256) {
        int n = lo + i;
        int r = (n < N_NODES) ? row_ofs[n] : 0;
        cur[i] = r + rel[i];
    }
    __syncthreads();

    int q0 = chunk * QPC;
    int q1 = q0 + QPC;
    for (int q = q0 + threadIdx.x; q < q1; q += 256) {
        int4 s = src4[q];
        int4 d = dst4[q];
        unsigned a0 = (unsigned)(d.x - lo); if (a0 < SLICE) esrc[atomicAdd(&cur[a0], 1)] = s.x;
        unsigned a1 = (unsigned)(d.y - lo); if (a1 < SLICE) esrc[atomicAdd(&cur[a1], 1)] = s.y;
        unsigned a2 = (unsigned)(d.z - lo); if (a2 < SLICE) esrc[atomicAdd(&cur[a2], 1)] = s.z;
        unsigned a3 = (unsigned)(d.w - lo); if (a3 < SLICE) esrc[atomicAdd(&cur[a3], 1)] = s.w;
    }
}

// ---------------- fold Wc = w_red @ w2, bc = b_red @ w2 ----------------
__global__ __launch_bounds__(128) void wc_kernel(const float* __restrict__ w_red,
                                                 const float* __restrict__ b_red,
                                                 const float* __restrict__ w2,
                                                 float* __restrict__ Wc,
                                                 float* __restrict__ bc) {
    int j = threadIdx.x;   // 0..127
    int i = blockIdx.x;    // 0..256 (block 256 computes bc)
    const float* vin = (i < IN_DIM) ? (w_red + (size_t)i * OUT_DIM) : b_red;
    float s = 0.f;
    for (int k = 0; k < OUT_DIM; ++k) s = fmaf(vin[k], w2[k * OUT_DIM + j], s);
    if (i < IN_DIM) Wc[i * OUT_DIM + j] = s;
    else            bc[j] = s;
}

// ---------------- z = out_norm * (feat @ Wc + bc) ----------------
// Grid = (782 row-tiles) x (2 col-halves) = 1564 blocks -> 6.1 blocks/CU
// (R5/R6's 782 capped occupancy at 37.5%). Single-buffer 2-barrier loop keeps
// VGPR ~50 (R6's reg-staged dbuf hit 232 VGPR -> 8.5% occupancy).
// As[64][36]: float4 staging (aligned, 2-way=free); compute reads use
// ROW-INTERLEAVED micro-tile (rows rg+16i) -> scalar reads land in 4 distinct
// banks, conflict-free. Bs[32][68]: float4 stage/read, 2-way max.
__global__ __launch_bounds__(256) void gemm_z(const float* __restrict__ feat,
                                              const float* __restrict__ Wc,
                                              const float* __restrict__ bc,
                                              const float* __restrict__ out_norm,
                                              float* __restrict__ z) {
    __shared__ float As[BM][BK + 4];     // [row][k], stride 36
    __shared__ float Bs[BK][BN + 4];     // [k][col], stride 68

    int t  = threadIdx.x;
    int bm = blockIdx.x * BM;
    int bn_base = blockIdx.y * BN;
    int cg = t & 15;       // cols cg*4 .. +3
    int rg = t >> 4;       // rows rg + 16*i, i=0..3
    int ar = t >> 3;       // staging A: rows ar, ar+32
    int ak = (t & 7) * 4;  // staging A: k-offset
    int bn = (t & 15) * 4; // staging B: cols bn..bn+3
    int bk = t >> 4;       // staging B: rows bk, bk+16

    int gm0 = bm + ar;
    int gm1 = bm + ar + 32;
    const float* fp0 = feat + (size_t)gm0 * IN_DIM + ak;
    const float* fp1 = feat + (size_t)gm1 * IN_DIM + ak;
    const float4 zf4 = make_float4(0.f, 0.f, 0.f, 0.f);

    float acc[4][4];
#pragma unroll
    for (int i = 0; i < 4; ++i)
#pragma unroll
        for (int j = 0; j < 4; ++j) acc[i][j] = 0.f;

    for (int k0 = 0; k0 < IN_DIM; k0 += BK) {
        float4 av0 = (gm0 < N_NODES) ? *(const float4*)(fp0 + k0) : zf4;
        float4 av1 = (gm1 < N_NODES) ? *(const float4*)(fp1 + k0) : zf4;
        float4 bv0 = *(const float4*)&Wc[(size_t)(k0 + bk) * OUT_DIM + bn_base + bn];
        float4 bv1 = *(const float4*)&Wc[(size_t)(k0 + bk + 16) * OUT_DIM + bn_base + bn];
        *(float4*)&As[ar][ak]      = av0;
        *(float4*)&As[ar + 32][ak] = av1;
        *(float4*)&Bs[bk][bn]      = bv0;
        *(float4*)&Bs[bk + 16][bn] = bv1;
        __syncthreads();

#pragma unroll
        for (int k = 0; k < BK; ++k) {
            float a0 = As[rg     ][k];
            float a1 = As[rg + 16][k];
            float a2 = As[rg + 32][k];
            float a3 = As[rg + 48][k];
            float4 b4 = *(const float4*)&Bs[k][cg * 4];
            float bb[4] = {b4.x, b4.y, b4.z, b4.w};
#pragma unroll
            for (int j = 0; j < 4; ++j) {
                acc[0][j] = fmaf(a0, bb[j], acc[0][j]);
                acc[1][j] = fmaf(a1, bb[j], acc[1][j]);
                acc[2][j] = fmaf(a2, bb[j], acc[2][j]);
                acc[3][j] = fmaf(a3, bb[j], acc[3][j]);
            }
        }
        __syncthreads();
    }

#pragma unroll
    for (int i = 0; i < 4; ++i) {
        int gm = bm + rg + 16 * i;
        if (gm < N_NODES) {
            float on = out_norm[gm];
            int col = bn_base + cg * 4;
            float4 o;
            o.x = on * (acc[i][0] + bc[col + 0]);
            o.y = on * (acc[i][1] + bc[col + 1]);
            o.z = on * (acc[i][2] + bc[col + 2]);
            o.w = on * (acc[i][3] + bc[col + 3]);
            *(float4*)&z[(size_t)gm * OUT_DIM + col] = o;
        }
    }
}

// ---------------- pull-model aggregate + fused in_norm/bias/leaky_relu ----------------
__global__ __launch_bounds__(128) void gather_kernel(const float* __restrict__ z,
                                                     const int* __restrict__ esrc,
                                                     const int* __restrict__ row_ofs,
                                                     const float* __restrict__ in_norm,
                                                     const float* __restrict__ b2,
                                                     float* __restrict__ h) {
    int n = blockIdx.x;
    int j = threadIdx.x;
    int e0 = row_ofs[n];
    int e1 = row_ofs[n + 1];
    float acc = 0.f;
    int e = e0;
    for (; e + 4 <= e1; e += 4) {
        int sa = esrc[e + 0];
        int sb = esrc[e + 1];
        int sc = esrc[e + 2];
        int sd = esrc[e + 3];
        float va = z[(size_t)sa * OUT_DIM + j];
        float vb = z[(size_t)sb * OUT_DIM + j];
        float vc = z[(size_t)sc * OUT_DIM + j];
        float vd = z[(size_t)sd * OUT_DIM + j];
        acc += (va + vb) + (vc + vd);
    }
    for (; e < e1; ++e) acc += z[(size_t)esrc[e] * OUT_DIM + j];
    float hv = in_norm[n] * acc + b2[j];
    h[(size_t)n * OUT_DIM + j] = (hv > 0.f) ? hv : NEG_SLOPE * hv;
}

// ---------------- per-graph readout (graph_ids sorted) ----------------
__global__ __launch_bounds__(128) void readout_kernel(const float* __restrict__ h,
                                                      const int* __restrict__ gids,
                                                      float* __restrict__ g) {
    int j    = threadIdx.x;
    int n0   = blockIdx.x * RCHUNK;
    int nend = n0 + RCHUNK;
    if (nend > N_NODES) nend = N_NODES;
    float acc = 0.f;
    int   cur = gids[n0];
    for (int n = n0; n < nend; ++n) {
        int gid = gids[n];
        if (gid != cur) {
            atomicAdd(&g[cur * OUT_DIM + j], acc);
            acc = 0.f;
            cur = gid;
        }
        acc += h[(size_t)n * OUT_DIM + j];
    }
    atomicAdd(&g[cur * OUT_DIM + j], acc);
}

// ---------------- classifier: out = g @ w_cls + b_cls ----------------
__global__ __launch_bounds__(256) void cls_kernel(const float* __restrict__ g,
                                                  const float* __restrict__ w_cls,
                                                  const float* __restrict__ b_cls,
                                                  float* __restrict__ out) {
    int t  = threadIdx.x;
    int gr = t >> 1;
    int c  = t & 1;
    float s = b_cls[c];
    for (int k = 0; k < OUT_DIM; ++k) s = fmaf(g[gr * OUT_DIM + k], w_cls[k * 2 + c], s);
    out[t] = s;
}

extern "C" void kernel_launch(void* const* d_in, const int* in_sizes, int n_in,
                              void* d_out, int out_size, void* d_ws, size_t ws_size,
                              hipStream_t stream) {
    const float* feat  = (const float*)d_in[0];
    const int*   src   = (const int*)d_in[1];
    const int*   dst   = (const int*)d_in[2];
    const int*   gids  = (const int*)d_in[3];
    const float* w_red = (const float*)d_in[4];
    const float* b_red = (const float*)d_in[5];
    const float* w_gcn = (const float*)d_in[6];
    const float* b_gcn = (const float*)d_in[7];
    const float* w_cls = (const float*)d_in[8];
    const float* b_cls = (const float*)d_in[9];
    float* out = (float*)d_out;

    // workspace layout
    float* z        = (float*)d_ws;                       // 6.4M floats (25.6MB)
    float* h        = z + (size_t)N_NODES * OUT_DIM;      // 6.4M floats (25.6MB)
    float* out_norm = h + (size_t)N_NODES * OUT_DIM;      // 50000
    float* in_norm  = out_norm + N_NODES;                 // 50000
    int*   deg_in   = (int*)(in_norm + N_NODES);          // 50000 (compact)
    int*   row_ofs  = deg_in + N_NODES;                   // 50001
    int*   esrc     = row_ofs + N_NODES + 1;              // 800000
    int*   bsum     = esrc + N_EDGES;                     // NB_SCAN
    int*   bofs     = bsum + NB_SCAN;                     // NB_SCAN
    float* Wc       = (float*)(bofs + NB_SCAN);           // 32768
    float* bc       = Wc + IN_DIM * OUT_DIM;              // 128
    float* g        = bc + OUT_DIM;                       // 16384

    // per-chunk histogram replicas rep[2][NCHUNK][NTOT] = 25.7MB ALIAS z∪h
    // (deg/norm/build all complete before gemm_z writes z / gather writes h).
    int* rep = (int*)z;

    const float* w2 = w_gcn + 2 * OUT_DIM * OUT_DIM;      // layer 2 weights
    const float* b2 = b_gcn + 2 * OUT_DIM;                // layer 2 bias

    hipMemsetAsync(g, 0, (size_t)N_GRAPHS * OUT_DIM * sizeof(float), stream);

    deg_kernel<<<2 * NSLICE * NCHUNK, 256, 0, stream>>>((const int4*)src, (const int4*)dst, rep);
    norm_kernel<<<(N_NODES + 255) / 256, 256, 0, stream>>>(rep, out_norm, in_norm, deg_in);
    partial_kernel<<<NB_SCAN, 256, 0, stream>>>(deg_in, bsum);
    scan_bsums<<<1, 256, 0, stream>>>(bsum, bofs, row_ofs);
    fill_kernel<<<NB_SCAN, 256, 0, stream>>>(deg_in, bofs, row_ofs);
    build_kernel<<<NSLICE * NCHUNK, 256, 0, stream>>>((const int4*)src, (const int4*)dst,
                                                      row_ofs, rep, esrc);
    wc_kernel<<<IN_DIM + 1, OUT_DIM, 0, stream>>>(w_red, b_red, w2, Wc, bc);
    gemm_z<<<dim3((N_NODES + BM - 1) / BM, OUT_DIM / BN), 256, 0, stream>>>(feat, Wc, bc,
                                                                            out_norm, z);
    gather_kernel<<<N_NODES, 128, 0, stream>>>(z, esrc, row_ofs, in_norm, b2, h);
    readout_kernel<<<(N_NODES + RCHUNK - 1) / RCHUNK, 128, 0, stream>>>(h, gids, g);
    cls_kernel<<<1, 256, 0, stream>>>(g, w_cls, b_cls, out);
}

// Round 8
// 196.254 us; speedup vs baseline: 1.3312x; 1.1187x over previous
//
#include <hip/hip_runtime.h>

#define N_NODES 50000
#define N_EDGES 800000
#define N_GRAPHS 128
#define IN_DIM 256
#define OUT_DIM 128
#define NEG_SLOPE 0.01f

#define RCHUNK 64
#define NB_SCAN ((N_NODES + 255) / 256)   // 196 blocks for the scan

#define NSLICE 4
#define SLICE 12544                        // 4*12544 = 50176 >= N_NODES
#define NTOT (NSLICE * SLICE)              // 50176
#define NCHUNK 64
#define NE4 (N_EDGES / 4)                  // 200000 int4 quads
#define QPC (NE4 / NCHUNK)                 // 3125 quads per chunk

typedef __attribute__((ext_vector_type(8))) short bf16x8;
typedef __attribute__((ext_vector_type(4))) float f32x4;
typedef unsigned short ushort_t;

__device__ inline ushort_t f2b(float f) {          // fp32 -> bf16 bits, RNE
    union { float f; unsigned u; } c{f};
    unsigned r = c.u + 0x7FFFu + ((c.u >> 16) & 1u);
    return (ushort_t)(r >> 16);
}
__device__ inline float b2f(ushort_t u) {          // bf16 bits -> fp32
    union { unsigned u; float f; } c{(unsigned)u << 16};
    return c.f;
}

// ---------------- degree histograms: LDS slices, zero global atomics ----------------
__global__ __launch_bounds__(256) void deg_kernel(const int4* __restrict__ src4,
                                                  const int4* __restrict__ dst4,
                                                  int* __restrict__ rep) {
    __shared__ int bins[SLICE];
    int b     = blockIdx.x;
    int hist  = b >> 8;                  // 0: src (out-deg), 1: dst (in-deg)
    int rem   = b & 255;
    int slice = rem >> 6;
    int chunk = rem & 63;
    const int4* ea = hist ? dst4 : src4;
    int lo = slice * SLICE;

    for (int i = threadIdx.x; i < SLICE; i += 256) bins[i] = 0;
    __syncthreads();

    int q0 = chunk * QPC;
    int q1 = q0 + QPC;
    for (int q = q0 + threadIdx.x; q < q1; q += 256) {
        int4 e = ea[q];
        unsigned a0 = (unsigned)(e.x - lo); if (a0 < SLICE) atomicAdd(&bins[a0], 1);
        unsigned a1 = (unsigned)(e.y - lo); if (a1 < SLICE) atomicAdd(&bins[a1], 1);
        unsigned a2 = (unsigned)(e.z - lo); if (a2 < SLICE) atomicAdd(&bins[a2], 1);
        unsigned a3 = (unsigned)(e.w - lo); if (a3 < SLICE) atomicAdd(&bins[a3], 1);
    }
    __syncthreads();

    int* rp = rep + (size_t)(hist * NCHUNK + chunk) * NTOT + lo;
    for (int i = threadIdx.x; i < SLICE / 4; i += 256)
        *(int4*)&rp[i * 4] = *(const int4*)&bins[i * 4];
}

// ---------------- reduce replicas -> norms + deg_in; in-place chunk-prefix scan ----------------
__global__ __launch_bounds__(256) void norm_kernel(int* __restrict__ rep,
                                                   float* __restrict__ out_norm,
                                                   float* __restrict__ in_norm,
                                                   int* __restrict__ deg_in_tot) {
    int i = blockIdx.x * 256 + threadIdx.x;
    if (i < N_NODES) {
        int so = 0;
#pragma unroll
        for (int c = 0; c < NCHUNK; ++c) so += rep[(size_t)c * NTOT + i];
        int si = 0;
#pragma unroll
        for (int c = 0; c < NCHUNK; ++c) {       // exclusive scan, in place
            size_t off = (size_t)(NCHUNK + c) * NTOT + i;
            int v = rep[off];
            rep[off] = si;
            si += v;
        }
        deg_in_tot[i] = si;
        int dq = so > 1 ? so : 1;
        int di = si > 1 ? si : 1;
        out_norm[i] = rsqrtf((float)dq);
        in_norm[i]  = rsqrtf((float)di);
    }
}

// ---------------- multi-block scan phase 1: per-block sums ----------------
__global__ __launch_bounds__(256) void partial_kernel(const int* __restrict__ deg_in,
                                                      int* __restrict__ bsum) {
    __shared__ int red[256];
    int t   = threadIdx.x;
    int idx = blockIdx.x * 256 + t;
    red[t] = (idx < N_NODES) ? deg_in[idx] : 0;
    __syncthreads();
    for (int off = 128; off > 0; off >>= 1) {
        if (t < off) red[t] += red[t + off];
        __syncthreads();
    }
    if (t == 0) bsum[blockIdx.x] = red[0];
}

// ---------------- phase 2: scan the 196 block sums (one block) ----------------
__global__ __launch_bounds__(256) void scan_bsums(const int* __restrict__ bsum,
                                                  int* __restrict__ bofs,
                                                  int* __restrict__ row_ofs) {
    __shared__ int sh[256];
    int t = threadIdx.x;
    int v = (t < NB_SCAN) ? bsum[t] : 0;
    sh[t] = v;
    __syncthreads();
    for (int off = 1; off < 256; off <<= 1) {
        int a = sh[t];
        int b = (t >= off) ? sh[t - off] : 0;
        __syncthreads();
        sh[t] = a + b;
        __syncthreads();
    }
    if (t < NB_SCAN) bofs[t] = sh[t] - v;                    // exclusive
    if (t == 255)    row_ofs[N_NODES] = sh[NB_SCAN - 1];     // total (= N_EDGES)
}

// ---------------- phase 3: block-local scan + offset -> row_ofs ----------------
__global__ __launch_bounds__(256) void fill_kernel(const int* __restrict__ deg_in,
                                                   const int* __restrict__ bofs,
                                                   int* __restrict__ row_ofs) {
    __shared__ int sh[256];
    int t   = threadIdx.x;
    int idx = blockIdx.x * 256 + t;
    int v   = (idx < N_NODES) ? deg_in[idx] : 0;
    sh[t] = v;
    __syncthreads();
    for (int off = 1; off < 256; off <<= 1) {
        int a = sh[t];
        int b = (t >= off) ? sh[t - off] : 0;
        __syncthreads();
        sh[t] = a + b;
        __syncthreads();
    }
    if (idx < N_NODES) row_ofs[idx] = bofs[blockIdx.x] + sh[t] - v;
}

// ---------------- chunked bucket fill: LDS cursors, zero global atomics ----------------
__global__ __launch_bounds__(256) void build_kernel(const int4* __restrict__ src4,
                                                    const int4* __restrict__ dst4,
                                                    const int* __restrict__ row_ofs,
                                                    const int* __restrict__ rep,
                                                    int* __restrict__ esrc) {
    __shared__ int cur[SLICE];
    int b     = blockIdx.x;
    int slice = b >> 6;
    int chunk = b & 63;
    int lo    = slice * SLICE;
    const int* rel = rep + (size_t)(NCHUNK + chunk) * NTOT + lo;

    for (int i = threadIdx.x; i < SLICE; i += 256) {
        int n = lo + i;
        int r = (n < N_NODES) ? row_ofs[n] : 0;
        cur[i] = r + rel[i];
    }
    __syncthreads();

    int q0 = chunk * QPC;
    int q1 = q0 + QPC;
    for (int q = q0 + threadIdx.x; q < q1; q += 256) {
        int4 s = src4[q];
        int4 d = dst4[q];
        unsigned a0 = (unsigned)(d.x - lo); if (a0 < SLICE) esrc[atomicAdd(&cur[a0], 1)] = s.x;
        unsigned a1 = (unsigned)(d.y - lo); if (a1 < SLICE) esrc[atomicAdd(&cur[a1], 1)] = s.y;
        unsigned a2 = (unsigned)(d.z - lo); if (a2 < SLICE) esrc[atomicAdd(&cur[a2], 1)] = s.z;
        unsigned a3 = (unsigned)(d.w - lo); if (a3 < SLICE) esrc[atomicAdd(&cur[a3], 1)] = s.w;
    }
}

// ---------------- fold: Wcs[n][k] = bf16(sum_c w_red[k][c] w2[c][n]), bc = b_red @ w2 ----------------
__global__ __launch_bounds__(128) void wc_kernel(const float* __restrict__ w_red,
                                                 const float* __restrict__ b_red,
                                                 const float* __restrict__ w2,
                                                 ushort_t* __restrict__ Wcs,
                                                 float* __restrict__ bc) {
    int j = threadIdx.x;   // n: 0..127
    int i = blockIdx.x;    // k: 0..256 (block 256 computes bc)
    const float* vin = (i < IN_DIM) ? (w_red + (size_t)i * OUT_DIM) : b_red;
    float s = 0.f;
    for (int k = 0; k < OUT_DIM; ++k) s = fmaf(vin[k], w2[k * OUT_DIM + j], s);
    if (i < IN_DIM) Wcs[(size_t)j * IN_DIM + i] = f2b(s);   // transposed, bf16
    else            bc[j] = s;
}

// ---------------- z = bf16(out_norm * (feat @ Wc + bc)) via MFMA ----------------
// 4 waves/block, each wave: 16 rows x 128 cols, K=256. No LDS.
// Fragments (m89-verified): A: m=lane&15, k=(lane>>4)*8+i ; B: n=lane&15, same k ;
// D: m=(lane>>4)*4+r, n=lane&15.
__global__ __launch_bounds__(256) void gemm_z(const float* __restrict__ feat,
                                              const ushort_t* __restrict__ Wcs,
                                              const float* __restrict__ bc,
                                              const float* __restrict__ out_norm,
                                              ushort_t* __restrict__ zb) {
    int t    = threadIdx.x;
    int lane = t & 63;
    int wv   = t >> 6;                       // wave 0..3
    int bm   = blockIdx.x * 64 + wv * 16;    // this wave's 16-row strip
    int mrow = lane & 15;
    int kg   = lane >> 4;                    // 0..3
    int gm   = bm + mrow;

    f32x4 acc[8];
#pragma unroll
    for (int nt = 0; nt < 8; ++nt) acc[nt] = (f32x4){0.f, 0.f, 0.f, 0.f};

    const float* fp = feat + (size_t)gm * IN_DIM + kg * 8;

#pragma unroll
    for (int kt = 0; kt < IN_DIM / 32; ++kt) {
        int k0 = kt * 32;
        bf16x8 af;
        if (gm < N_NODES) {
            float4 a0 = *(const float4*)(fp + k0);
            float4 a1 = *(const float4*)(fp + k0 + 4);
            af[0] = (short)f2b(a0.x); af[1] = (short)f2b(a0.y);
            af[2] = (short)f2b(a0.z); af[3] = (short)f2b(a0.w);
            af[4] = (short)f2b(a1.x); af[5] = (short)f2b(a1.y);
            af[6] = (short)f2b(a1.z); af[7] = (short)f2b(a1.w);
        } else {
            af = (bf16x8){0, 0, 0, 0, 0, 0, 0, 0};
        }
#pragma unroll
        for (int nt = 0; nt < 8; ++nt) {
            bf16x8 bf = *(const bf16x8*)&Wcs[(size_t)(nt * 16 + mrow) * IN_DIM + k0 + kg * 8];
            acc[nt] = __builtin_amdgcn_mfma_f32_16x16x32_bf16(af, bf, acc[nt], 0, 0, 0);
        }
    }

    // epilogue: rows bm + kg*4 + r, col nt*16 + mrow
    float on[4];
#pragma unroll
    for (int r = 0; r < 4; ++r) {
        int row = bm + kg * 4 + r;
        on[r] = (row < N_NODES) ? out_norm[row] : 0.f;
    }
#pragma unroll
    for (int nt = 0; nt < 8; ++nt) {
        int col = nt * 16 + mrow;
        float bcv = bc[col];
#pragma unroll
        for (int r = 0; r < 4; ++r) {
            int row = bm + kg * 4 + r;
            if (row < N_NODES)
                zb[(size_t)row * OUT_DIM + col] = f2b(on[r] * (acc[nt][r] + bcv));
        }
    }
}

// ---------------- pull-model aggregate + fused in_norm/bias/leaky_relu (bf16 io) ----------------
__global__ __launch_bounds__(128) void gather_kernel(const ushort_t* __restrict__ zb,
                                                     const int* __restrict__ esrc,
                                                     const int* __restrict__ row_ofs,
                                                     const float* __restrict__ in_norm,
                                                     const float* __restrict__ b2,
                                                     ushort_t* __restrict__ hb) {
    int n = blockIdx.x;
    int j = threadIdx.x;
    int e0 = row_ofs[n];
    int e1 = row_ofs[n + 1];
    float acc = 0.f;
    int e = e0;
    for (; e + 4 <= e1; e += 4) {
        int sa = esrc[e + 0];
        int sb = esrc[e + 1];
        int sc = esrc[e + 2];
        int sd = esrc[e + 3];
        float va = b2f(zb[(size_t)sa * OUT_DIM + j]);
        float vb = b2f(zb[(size_t)sb * OUT_DIM + j]);
        float vc = b2f(zb[(size_t)sc * OUT_DIM + j]);
        float vd = b2f(zb[(size_t)sd * OUT_DIM + j]);
        acc += (va + vb) + (vc + vd);
    }
    for (; e < e1; ++e) acc += b2f(zb[(size_t)esrc[e] * OUT_DIM + j]);
    float hv = in_norm[n] * acc + b2[j];
    hv = (hv > 0.f) ? hv : NEG_SLOPE * hv;
    hb[(size_t)n * OUT_DIM + j] = f2b(hv);
}

// ---------------- per-graph readout (graph_ids sorted, bf16 in) ----------------
__global__ __launch_bounds__(128) void readout_kernel(const ushort_t* __restrict__ hb,
                                                      const int* __restrict__ gids,
                                                      float* __restrict__ g) {
    int j    = threadIdx.x;
    int n0   = blockIdx.x * RCHUNK;
    int nend = n0 + RCHUNK;
    if (nend > N_NODES) nend = N_NODES;
    float acc = 0.f;
    int   cur = gids[n0];
    for (int n = n0; n < nend; ++n) {
        int gid = gids[n];
        if (gid != cur) {
            atomicAdd(&g[cur * OUT_DIM + j], acc);
            acc = 0.f;
            cur = gid;
        }
        acc += b2f(hb[(size_t)n * OUT_DIM + j]);
    }
    atomicAdd(&g[cur * OUT_DIM + j], acc);
}

// ---------------- classifier: out = g @ w_cls + b_cls ----------------
__global__ __launch_bounds__(256) void cls_kernel(const float* __restrict__ g,
                                                  const float* __restrict__ w_cls,
                                                  const float* __restrict__ b_cls,
                                                  float* __restrict__ out) {
    int t  = threadIdx.x;
    int gr = t >> 1;
    int c  = t & 1;
    float s = b_cls[c];
    for (int k = 0; k < OUT_DIM; ++k) s = fmaf(g[gr * OUT_DIM + k], w_cls[k * 2 + c], s);
    out[t] = s;
}

extern "C" void kernel_launch(void* const* d_in, const int* in_sizes, int n_in,
                              void* d_out, int out_size, void* d_ws, size_t ws_size,
                              hipStream_t stream) {
    const float* feat  = (const float*)d_in[0];
    const int*   src   = (const int*)d_in[1];
    const int*   dst   = (const int*)d_in[2];
    const int*   gids  = (const int*)d_in[3];
    const float* w_red = (const float*)d_in[4];
    const float* b_red = (const float*)d_in[5];
    const float* w_gcn = (const float*)d_in[6];
    const float* b_gcn = (const float*)d_in[7];
    const float* w_cls = (const float*)d_in[8];
    const float* b_cls = (const float*)d_in[9];
    float* out = (float*)d_out;

    // workspace layout (z/h regions sized as fp32 but used as bf16 -> half used)
    float* z        = (float*)d_ws;                       // 25.6MB region, zb uses 12.8
    float* h        = z + (size_t)N_NODES * OUT_DIM;      // 25.6MB region, hb uses 12.8
    float* out_norm = h + (size_t)N_NODES * OUT_DIM;      // 50000
    float* in_norm  = out_norm + N_NODES;                 // 50000
    int*   deg_in   = (int*)(in_norm + N_NODES);          // 50000 (compact)
    int*   row_ofs  = deg_in + N_NODES;                   // 50001
    int*   esrc     = row_ofs + N_NODES + 1;              // 800000
    int*   bsum     = esrc + N_EDGES;                     // NB_SCAN
    int*   bofs     = bsum + NB_SCAN;                     // NB_SCAN
    ushort_t* Wcs   = (ushort_t*)(bofs + NB_SCAN);        // 32768 bf16
    float* bc       = (float*)(Wcs + IN_DIM * OUT_DIM);   // 128
    float* g        = bc + OUT_DIM;                       // 16384

    ushort_t* zb = (ushort_t*)z;
    ushort_t* hb = (ushort_t*)h;

    // per-chunk histogram replicas rep[2][NCHUNK][NTOT] = 25.7MB ALIAS z∪h
    // (deg/norm/build all complete before gemm_z writes zb / gather writes hb).
    int* rep = (int*)z;

    const float* w2 = w_gcn + 2 * OUT_DIM * OUT_DIM;      // layer 2 weights
    const float* b2 = b_gcn + 2 * OUT_DIM;                // layer 2 bias

    hipMemsetAsync(g, 0, (size_t)N_GRAPHS * OUT_DIM * sizeof(float), stream);

    deg_kernel<<<2 * NSLICE * NCHUNK, 256, 0, stream>>>((const int4*)src, (const int4*)dst, rep);
    norm_kernel<<<(N_NODES + 255) / 256, 256, 0, stream>>>(rep, out_norm, in_norm, deg_in);
    partial_kernel<<<NB_SCAN, 256, 0, stream>>>(deg_in, bsum);
    scan_bsums<<<1, 256, 0, stream>>>(bsum, bofs, row_ofs);
    fill_kernel<<<NB_SCAN, 256, 0, stream>>>(deg_in, bofs, row_ofs);
    build_kernel<<<NSLICE * NCHUNK, 256, 0, stream>>>((const int4*)src, (const int4*)dst,
                                                      row_ofs, rep, esrc);
    wc_kernel<<<IN_DIM + 1, OUT_DIM, 0, stream>>>(w_red, b_red, w2, Wcs, bc);
    gemm_z<<<(N_NODES + 63) / 64, 256, 0, stream>>>(feat, Wcs, bc, out_norm, zb);
    gather_kernel<<<N_NODES, 128, 0, stream>>>(zb, esrc, row_ofs, in_norm, b2, hb);
    readout_kernel<<<(N_NODES + RCHUNK - 1) / RCHUNK, 128, 0, stream>>>(hb, gids, g);
    cls_kernel<<<1, 256, 0, stream>>>(g, w_cls, b_cls, out);
}

// Round 9
// 175.820 us; speedup vs baseline: 1.4859x; 1.1162x over previous
//
#include <hip/hip_runtime.h>

#define N_NODES 50000
#define N_EDGES 800000
#define N_GRAPHS 128
#define IN_DIM 256
#define OUT_DIM 128
#define NEG_SLOPE 0.01f

#define RCHUNK 64
#define NB_SCAN ((N_NODES + 255) / 256)   // 196 blocks for the scan

#define NSLICE 4
#define SLICE 12544                        // 4*12544 = 50176 >= N_NODES
#define NTOT (NSLICE * SLICE)              // 50176
#define NCHUNK 64
#define NE4 (N_EDGES / 4)                  // 200000 int4 quads
#define QPC (NE4 / NCHUNK)                 // 3125 quads per chunk

typedef __attribute__((ext_vector_type(8))) short bf16x8;
typedef __attribute__((ext_vector_type(4))) float f32x4;
typedef unsigned short ushort_t;
typedef unsigned int uint_t;

__device__ inline ushort_t f2b(float f) {          // fp32 -> bf16 bits, RNE
    union { float f; unsigned u; } c{f};
    unsigned r = c.u + 0x7FFFu + ((c.u >> 16) & 1u);
    return (ushort_t)(r >> 16);
}
__device__ inline float b2f(ushort_t u) {          // bf16 bits -> fp32
    union { unsigned u; float f; } c{(unsigned)u << 16};
    return c.f;
}
__device__ inline float blo(uint_t v) {            // low bf16 of packed pair
    union { unsigned u; float f; } c{v << 16};
    return c.f;
}
__device__ inline float bhi(uint_t v) {            // high bf16 of packed pair
    union { unsigned u; float f; } c{v & 0xFFFF0000u};
    return c.f;
}

// ---------------- degree histograms: LDS slices, zero global atomics ----------------
__global__ __launch_bounds__(256) void deg_kernel(const int4* __restrict__ src4,
                                                  const int4* __restrict__ dst4,
                                                  int* __restrict__ rep) {
    __shared__ int bins[SLICE];
    int b     = blockIdx.x;
    int hist  = b >> 8;                  // 0: src (out-deg), 1: dst (in-deg)
    int rem   = b & 255;
    int slice = rem >> 6;
    int chunk = rem & 63;
    const int4* ea = hist ? dst4 : src4;
    int lo = slice * SLICE;

    for (int i = threadIdx.x; i < SLICE; i += 256) bins[i] = 0;
    __syncthreads();

    int q0 = chunk * QPC;
    int q1 = q0 + QPC;
    for (int q = q0 + threadIdx.x; q < q1; q += 256) {
        int4 e = ea[q];
        unsigned a0 = (unsigned)(e.x - lo); if (a0 < SLICE) atomicAdd(&bins[a0], 1);
        unsigned a1 = (unsigned)(e.y - lo); if (a1 < SLICE) atomicAdd(&bins[a1], 1);
        unsigned a2 = (unsigned)(e.z - lo); if (a2 < SLICE) atomicAdd(&bins[a2], 1);
        unsigned a3 = (unsigned)(e.w - lo); if (a3 < SLICE) atomicAdd(&bins[a3], 1);
    }
    __syncthreads();

    int* rp = rep + (size_t)(hist * NCHUNK + chunk) * NTOT + lo;
    for (int i = threadIdx.x; i < SLICE / 4; i += 256)
        *(int4*)&rp[i * 4] = *(const int4*)&bins[i * 4];
}

// ---------------- reduce replicas -> norms + deg_in; in-place chunk-prefix scan ----------------
__global__ __launch_bounds__(256) void norm_kernel(int* __restrict__ rep,
                                                   float* __restrict__ out_norm,
                                                   float* __restrict__ in_norm,
                                                   int* __restrict__ deg_in_tot) {
    int i = blockIdx.x * 256 + threadIdx.x;
    if (i < N_NODES) {
        int so = 0;
#pragma unroll
        for (int c = 0; c < NCHUNK; ++c) so += rep[(size_t)c * NTOT + i];
        int si = 0;
#pragma unroll
        for (int c = 0; c < NCHUNK; ++c) {       // exclusive scan, in place
            size_t off = (size_t)(NCHUNK + c) * NTOT + i;
            int v = rep[off];
            rep[off] = si;
            si += v;
        }
        deg_in_tot[i] = si;
        int dq = so > 1 ? so : 1;
        int di = si > 1 ? si : 1;
        out_norm[i] = rsqrtf((float)dq);
        in_norm[i]  = rsqrtf((float)di);
    }
}

// ---------------- multi-block scan phase 1: per-block sums ----------------
__global__ __launch_bounds__(256) void partial_kernel(const int* __restrict__ deg_in,
                                                      int* __restrict__ bsum) {
    __shared__ int red[256];
    int t   = threadIdx.x;
    int idx = blockIdx.x * 256 + t;
    red[t] = (idx < N_NODES) ? deg_in[idx] : 0;
    __syncthreads();
    for (int off = 128; off > 0; off >>= 1) {
        if (t < off) red[t] += red[t + off];
        __syncthreads();
    }
    if (t == 0) bsum[blockIdx.x] = red[0];
}

// ---------------- phase 2: scan the 196 block sums (one block) ----------------
__global__ __launch_bounds__(256) void scan_bsums(const int* __restrict__ bsum,
                                                  int* __restrict__ bofs,
                                                  int* __restrict__ row_ofs) {
    __shared__ int sh[256];
    int t = threadIdx.x;
    int v = (t < NB_SCAN) ? bsum[t] : 0;
    sh[t] = v;
    __syncthreads();
    for (int off = 1; off < 256; off <<= 1) {
        int a = sh[t];
        int b = (t >= off) ? sh[t - off] : 0;
        __syncthreads();
        sh[t] = a + b;
        __syncthreads();
    }
    if (t < NB_SCAN) bofs[t] = sh[t] - v;                    // exclusive
    if (t == 255)    row_ofs[N_NODES] = sh[NB_SCAN - 1];     // total (= N_EDGES)
}

// ---------------- phase 3: block-local scan + offset -> row_ofs ----------------
__global__ __launch_bounds__(256) void fill_kernel(const int* __restrict__ deg_in,
                                                   const int* __restrict__ bofs,
                                                   int* __restrict__ row_ofs) {
    __shared__ int sh[256];
    int t   = threadIdx.x;
    int idx = blockIdx.x * 256 + t;
    int v   = (idx < N_NODES) ? deg_in[idx] : 0;
    sh[t] = v;
    __syncthreads();
    for (int off = 1; off < 256; off <<= 1) {
        int a = sh[t];
        int b = (t >= off) ? sh[t - off] : 0;
        __syncthreads();
        sh[t] = a + b;
        __syncthreads();
    }
    if (idx < N_NODES) row_ofs[idx] = bofs[blockIdx.x] + sh[t] - v;
}

// ---------------- chunked bucket fill: LDS cursors, zero global atomics ----------------
__global__ __launch_bounds__(256) void build_kernel(const int4* __restrict__ src4,
                                                    const int4* __restrict__ dst4,
                                                    const int* __restrict__ row_ofs,
                                                    const int* __restrict__ rep,
                                                    int* __restrict__ esrc) {
    __shared__ int cur[SLICE];
    int b     = blockIdx.x;
    int slice = b >> 6;
    int chunk = b & 63;
    int lo    = slice * SLICE;
    const int* rel = rep + (size_t)(NCHUNK + chunk) * NTOT + lo;

    for (int i = threadIdx.x; i < SLICE; i += 256) {
        int n = lo + i;
        int r = (n < N_NODES) ? row_ofs[n] : 0;
        cur[i] = r + rel[i];
    }
    __syncthreads();

    int q0 = chunk * QPC;
    int q1 = q0 + QPC;
    for (int q = q0 + threadIdx.x; q < q1; q += 256) {
        int4 s = src4[q];
        int4 d = dst4[q];
        unsigned a0 = (unsigned)(d.x - lo); if (a0 < SLICE) esrc[atomicAdd(&cur[a0], 1)] = s.x;
        unsigned a1 = (unsigned)(d.y - lo); if (a1 < SLICE) esrc[atomicAdd(&cur[a1], 1)] = s.y;
        unsigned a2 = (unsigned)(d.z - lo); if (a2 < SLICE) esrc[atomicAdd(&cur[a2], 1)] = s.z;
        unsigned a3 = (unsigned)(d.w - lo); if (a3 < SLICE) esrc[atomicAdd(&cur[a3], 1)] = s.w;
    }
}

// ---------------- fold: Wcs[n][k] = bf16(sum_c w_red[k][c] w2[c][n]), bc = b_red @ w2 ----------------
__global__ __launch_bounds__(128) void wc_kernel(const float* __restrict__ w_red,
                                                 const float* __restrict__ b_red,
                                                 const float* __restrict__ w2,
                                                 ushort_t* __restrict__ Wcs,
                                                 float* __restrict__ bc) {
    int j = threadIdx.x;   // n: 0..127
    int i = blockIdx.x;    // k: 0..256 (block 256 computes bc)
    const float* vin = (i < IN_DIM) ? (w_red + (size_t)i * OUT_DIM) : b_red;
    float s = 0.f;
    for (int k = 0; k < OUT_DIM; ++k) s = fmaf(vin[k], w2[k * OUT_DIM + j], s);
    if (i < IN_DIM) Wcs[(size_t)j * IN_DIM + i] = f2b(s);   // transposed, bf16
    else            bc[j] = s;
}

// ---------------- z = bf16(out_norm * (feat @ Wc + bc)) via MFMA, LDS-B ----------------
// Grid = 782 x 2 col-halves. Block: 4 waves, wave = 16 rows x 64 cols.
// B panel (64 cols x 256 k bf16 = 32KB) staged in LDS with XOR swizzle
// (byte ^= ((row&7)<<4)) -> ds_read_b128 on lgkm counter, decoupled from the
// HBM A-loads on vmcnt (in-order vmcnt was R8's serialization). A is 2-deep
// register-pipelined. Fragments (m89): A m=lane&15,k=(lane>>4)*8+i; B n=lane&15
// same k; D row=(lane>>4)*4+r, col=lane&15.
__global__ __launch_bounds__(256) void gemm_z(const float* __restrict__ feat,
                                              const ushort_t* __restrict__ Wcs,
                                              const float* __restrict__ bc,
                                              const float* __restrict__ out_norm,
                                              ushort_t* __restrict__ zb) {
    __shared__ ushort_t Bs[64 * IN_DIM];     // 32KB, 512B per col-row, swizzled
    int t    = threadIdx.x;
    int lane = t & 63;
    int wv   = t >> 6;
    int bm   = blockIdx.x * 64 + wv * 16;
    int bn0  = blockIdx.y * 64;
    int mrow = lane & 15;
    int kg   = lane >> 4;
    int gm   = bm + mrow;

    // stage B: 8 passes x 256 threads x 16B (coalesced), swizzled dest
    {
        const char* wsrc = (const char*)(Wcs + (size_t)bn0 * IN_DIM);
        char* bdst = (char*)Bs;
#pragma unroll
        for (int p = 0; p < 8; ++p) {
            int d  = p * 4096 + t * 16;
            int ds = d ^ (((d >> 9) & 7) << 4);
            *(int4*)(bdst + ds) = *(const int4*)(wsrc + d);
        }
    }
    __syncthreads();

    f32x4 acc[4];
#pragma unroll
    for (int nt = 0; nt < 4; ++nt) acc[nt] = (f32x4){0.f, 0.f, 0.f, 0.f};

    // per-lane swizzled B offsets: addr(kt) = boff[nt] ^ (kt<<6)
    int boff[4];
#pragma unroll
    for (int nt = 0; nt < 4; ++nt) {
        int n = nt * 16 + mrow;
        boff[nt] = n * 512 + ((kg * 16) ^ ((n & 7) << 4));
    }
    const char* bsp = (const char*)Bs;

    bool valid = gm < N_NODES;
    const float* fp = feat + (size_t)(valid ? gm : 0) * IN_DIM + kg * 8;
    const float4 zf4 = make_float4(0.f, 0.f, 0.f, 0.f);

    float4 a0c = valid ? *(const float4*)(fp + 0) : zf4;
    float4 a1c = valid ? *(const float4*)(fp + 4) : zf4;
    float4 a0n = zf4, a1n = zf4;

#pragma unroll
    for (int kt = 0; kt < IN_DIM / 32; ++kt) {
        if (kt < IN_DIM / 32 - 1) {            // prefetch next kt (2-deep pipeline)
            a0n = valid ? *(const float4*)(fp + (kt + 1) * 32) : zf4;
            a1n = valid ? *(const float4*)(fp + (kt + 1) * 32 + 4) : zf4;
        }
        bf16x8 af;
        af[0] = (short)f2b(a0c.x); af[1] = (short)f2b(a0c.y);
        af[2] = (short)f2b(a0c.z); af[3] = (short)f2b(a0c.w);
        af[4] = (short)f2b(a1c.x); af[5] = (short)f2b(a1c.y);
        af[6] = (short)f2b(a1c.z); af[7] = (short)f2b(a1c.w);
#pragma unroll
        for (int nt = 0; nt < 4; ++nt) {
            bf16x8 bf = *(const bf16x8*)(bsp + (boff[nt] ^ (kt << 6)));
            acc[nt] = __builtin_amdgcn_mfma_f32_16x16x32_bf16(af, bf, acc[nt], 0, 0, 0);
        }
        a0c = a0n; a1c = a1n;
    }

    // epilogue: rows bm + kg*4 + r, col bn0 + nt*16 + mrow
    float on[4];
#pragma unroll
    for (int r = 0; r < 4; ++r) {
        int row = bm + kg * 4 + r;
        on[r] = (row < N_NODES) ? out_norm[row] : 0.f;
    }
#pragma unroll
    for (int nt = 0; nt < 4; ++nt) {
        int col = bn0 + nt * 16 + mrow;
        float bcv = bc[col];
#pragma unroll
        for (int r = 0; r < 4; ++r) {
            int row = bm + kg * 4 + r;
            if (row < N_NODES)
                zb[(size_t)row * OUT_DIM + col] = f2b(on[r] * (acc[nt][r] + bcv));
        }
    }
}

// ---------------- pull aggregate + fused in_norm/bias/leaky_relu (packed bf16 pairs) ----------------
// 4 waves/block, one node per wave; lane covers col pair {2*lane, 2*lane+1};
// one uint load per edge-row per lane = full 256B row per wave-instruction.
__global__ __launch_bounds__(256) void gather_kernel(const uint_t* __restrict__ zb2,
                                                     const int* __restrict__ esrc,
                                                     const int* __restrict__ row_ofs,
                                                     const float* __restrict__ in_norm,
                                                     const float* __restrict__ b2,
                                                     uint_t* __restrict__ hb2) {
    int n    = blockIdx.x * 4 + (threadIdx.x >> 6);
    int lane = threadIdx.x & 63;
    if (n >= N_NODES) return;
    int e0 = row_ofs[n];
    int e1 = row_ofs[n + 1];
    float acc0 = 0.f, acc1 = 0.f;
    int e = e0;
    for (; e + 4 <= e1; e += 4) {
        int sa = esrc[e + 0];
        int sb = esrc[e + 1];
        int sc = esrc[e + 2];
        int sd = esrc[e + 3];
        uint_t va = zb2[(size_t)sa * 64 + lane];
        uint_t vb = zb2[(size_t)sb * 64 + lane];
        uint_t vc = zb2[(size_t)sc * 64 + lane];
        uint_t vd = zb2[(size_t)sd * 64 + lane];
        acc0 += (blo(va) + blo(vb)) + (blo(vc) + blo(vd));
        acc1 += (bhi(va) + bhi(vb)) + (bhi(vc) + bhi(vd));
    }
    for (; e < e1; ++e) {
        uint_t v = zb2[(size_t)esrc[e] * 64 + lane];
        acc0 += blo(v);
        acc1 += bhi(v);
    }
    float inn = in_norm[n];
    float2 bj = *(const float2*)&b2[2 * lane];
    float h0 = fmaf(inn, acc0, bj.x);
    float h1 = fmaf(inn, acc1, bj.y);
    h0 = (h0 > 0.f) ? h0 : NEG_SLOPE * h0;
    h1 = (h1 > 0.f) ? h1 : NEG_SLOPE * h1;
    hb2[(size_t)n * 64 + lane] = (uint_t)f2b(h0) | ((uint_t)f2b(h1) << 16);
}

// ---------------- per-graph readout (graph_ids sorted, bf16 in) ----------------
__global__ __launch_bounds__(128) void readout_kernel(const ushort_t* __restrict__ hb,
                                                      const int* __restrict__ gids,
                                                      float* __restrict__ g) {
    int j    = threadIdx.x;
    int n0   = blockIdx.x * RCHUNK;
    int nend = n0 + RCHUNK;
    if (nend > N_NODES) nend = N_NODES;
    float acc = 0.f;
    int   cur = gids[n0];
    for (int n = n0; n < nend; ++n) {
        int gid = gids[n];
        if (gid != cur) {
            atomicAdd(&g[cur * OUT_DIM + j], acc);
            acc = 0.f;
            cur = gid;
        }
        acc += b2f(hb[(size_t)n * OUT_DIM + j]);
    }
    atomicAdd(&g[cur * OUT_DIM + j], acc);
}

// ---------------- classifier: out = g @ w_cls + b_cls ----------------
__global__ __launch_bounds__(256) void cls_kernel(const float* __restrict__ g,
                                                  const float* __restrict__ w_cls,
                                                  const float* __restrict__ b_cls,
                                                  float* __restrict__ out) {
    int t  = threadIdx.x;
    int gr = t >> 1;
    int c  = t & 1;
    float s = b_cls[c];
    for (int k = 0; k < OUT_DIM; ++k) s = fmaf(g[gr * OUT_DIM + k], w_cls[k * 2 + c], s);
    out[t] = s;
}

extern "C" void kernel_launch(void* const* d_in, const int* in_sizes, int n_in,
                              void* d_out, int out_size, void* d_ws, size_t ws_size,
                              hipStream_t stream) {
    const float* feat  = (const float*)d_in[0];
    const int*   src   = (const int*)d_in[1];
    const int*   dst   = (const int*)d_in[2];
    const int*   gids  = (const int*)d_in[3];
    const float* w_red = (const float*)d_in[4];
    const float* b_red = (const float*)d_in[5];
    const float* w_gcn = (const float*)d_in[6];
    const float* b_gcn = (const float*)d_in[7];
    const float* w_cls = (const float*)d_in[8];
    const float* b_cls = (const float*)d_in[9];
    float* out = (float*)d_out;

    // workspace layout (z/h regions sized as fp32 but used as bf16 -> half used)
    float* z        = (float*)d_ws;                       // 25.6MB region, zb uses 12.8
    float* h        = z + (size_t)N_NODES * OUT_DIM;      // 25.6MB region, hb uses 12.8
    float* out_norm = h + (size_t)N_NODES * OUT_DIM;      // 50000
    float* in_norm  = out_norm + N_NODES;                 // 50000
    int*   deg_in   = (int*)(in_norm + N_NODES);          // 50000 (compact)
    int*   row_ofs  = deg_in + N_NODES;                   // 50001
    int*   esrc     = row_ofs + N_NODES + 1;              // 800000
    int*   bsum     = esrc + N_EDGES;                     // NB_SCAN
    int*   bofs     = bsum + NB_SCAN;                     // NB_SCAN
    ushort_t* Wcs   = (ushort_t*)(bofs + NB_SCAN);        // 32768 bf16
    float* bc       = (float*)(Wcs + IN_DIM * OUT_DIM);   // 128
    float* g        = bc + OUT_DIM;                       // 16384

    ushort_t* zb = (ushort_t*)z;
    ushort_t* hb = (ushort_t*)h;

    // per-chunk histogram replicas rep[2][NCHUNK][NTOT] = 25.7MB ALIAS z∪h
    // (deg/norm/build all complete before gemm_z writes zb / gather writes hb).
    int* rep = (int*)z;

    const float* w2 = w_gcn + 2 * OUT_DIM * OUT_DIM;      // layer 2 weights
    const float* b2 = b_gcn + 2 * OUT_DIM;                // layer 2 bias

    hipMemsetAsync(g, 0, (size_t)N_GRAPHS * OUT_DIM * sizeof(float), stream);

    deg_kernel<<<2 * NSLICE * NCHUNK, 256, 0, stream>>>((const int4*)src, (const int4*)dst, rep);
    norm_kernel<<<(N_NODES + 255) / 256, 256, 0, stream>>>(rep, out_norm, in_norm, deg_in);
    partial_kernel<<<NB_SCAN, 256, 0, stream>>>(deg_in, bsum);
    scan_bsums<<<1, 256, 0, stream>>>(bsum, bofs, row_ofs);
    fill_kernel<<<NB_SCAN, 256, 0, stream>>>(deg_in, bofs, row_ofs);
    build_kernel<<<NSLICE * NCHUNK, 256, 0, stream>>>((const int4*)src, (const int4*)dst,
                                                      row_ofs, rep, esrc);
    wc_kernel<<<IN_DIM + 1, OUT_DIM, 0, stream>>>(w_red, b_red, w2, Wcs, bc);
    gemm_z<<<dim3((N_NODES + 63) / 64, 2), 256, 0, stream>>>(feat, Wcs, bc, out_norm, zb);
    gather_kernel<<<(N_NODES + 3) / 4, 256, 0, stream>>>((const uint_t*)zb, esrc, row_ofs,
                                                         in_norm, b2, (uint_t*)hb);
    readout_kernel<<<(N_NODES + RCHUNK - 1) / RCHUNK, 128, 0, stream>>>(hb, gids, g);
    cls_kernel<<<1, 256, 0, stream>>>(g, w_cls, b_cls, out);
}